// Round 13
// baseline (236.467 us; speedup 1.0000x reference)
//
#include <hip/hip_runtime.h>

// VectorQuantizer: fused MFMA bf16 filter + bit-exact numpy recheck + gather.
// x [64,64,64,64] f32 -> flat [N=262144, D=64]; emb [D=64, K=512].
// out = concat(quantized_st flat [16777216], loss [1]) as f32.
//
// R13: keep R12's spill-free per-wave state (2 row-tiles = 32 rows/wave,
// ~55-76 VGPR, WRITE_SIZE==output proven), but fix the two R12 regressions:
//  - 4-wave workgroups (256 thr), 128 rows/block, 2048 blocks = 8/CU:
//    escapes the per-CU workgroup-slot cap that pinned R12 at 30% occupancy
//    (1-wave WGs). VGPR<=128 tier -> 4 waves/SIMD.
//  - restore R11's B prefetch double-buffer: j+1 fragments in flight while
//    j's MFMAs run -> ~200cy L2 latency hidden in-wave AND across waves.
//  - XCD-bijective swizzle (2048%8==0); ovf-flag overflow (no calls in
//    sweep loops, R10); block-shared cl[2048] (expected ~220 entries).
//
// Exact numpy semantics (proven absmax 0.0 R2/R5-R12) on candidates:
//   dist = fl(fl(z2+e2[k]) - 2*dot), dot = sequential fmaf d=0..63,
//   z2 = np pairwise_sum, e2 = sequential d-ascending, argmin strict-<
//   first-occurrence == lexicographic u64 min of (distbits<<32)|k [dist>0].
// bf16 filter: t = fmaf(-2, acc, e2c) in BOTH sweeps; MARGIN=0.09 >>
// 2*max bf16-vs-np t-error (~0.04) (R6-R12 validated).
//
// ws layout (bytes):
//   0      : float  et[512*64]    131072  (f32 codebook, code-major)
//   131072 : float  e2[512]         2048  (np-order norms, exact)
//   133120 : u16    ebT[512*64]    65536  (bf16 codebook, code-major)
//   198656 : double partials[2048] 16384  (per-block loss partials)

#define NROWS 262144
#define D 64
#define K 512
#define MARGIN 0.09f
#define INF32 3.4e38f

#define WS_ET 0
#define WS_E2 131072
#define WS_EBT 133120
#define WS_PARTIALS 198656

typedef __attribute__((ext_vector_type(8))) short bf16x8;
typedef __attribute__((ext_vector_type(4))) float f32x4;

__device__ inline unsigned short f2bf(float f) {  // RTNE, finite inputs
    unsigned u = __float_as_uint(f);
    u += 0x7fffu + ((u >> 16) & 1u);
    return (unsigned short)(u >> 16);
}
__device__ inline unsigned pack_bf2(float lo, float hi) {
    unsigned ulo = __float_as_uint(lo); ulo += 0x7fffu + ((ulo >> 16) & 1u);
    unsigned uhi = __float_as_uint(hi); uhi += 0x7fffu + ((uhi >> 16) & 1u);
    return (ulo >> 16) | (uhi & 0xffff0000u);
}
__device__ inline bf16x8 pack8(float4 p, float4 q) {
    union { unsigned u[4]; bf16x8 v; } r;
    r.u[0] = pack_bf2(p.x, p.y); r.u[1] = pack_bf2(p.z, p.w);
    r.u[2] = pack_bf2(q.x, q.y); r.u[3] = pack_bf2(q.z, q.w);
    return r.v;
}

// ---- K1: codebook prep (8 blocks x 64 threads, one code per thread) ----
__global__ void __launch_bounds__(64) vq_prep(const float* __restrict__ emb, char* ws) {
    float* e2 = (float*)(ws + WS_E2);
    float* et = (float*)(ws + WS_ET);
    unsigned short* ebT = (unsigned short*)(ws + WS_EBT);
    int k = blockIdx.x * 64 + threadIdx.x;
    float v0 = emb[k];
    et[k * D] = v0;
    ebT[k * D] = f2bf(v0);
    float s = __fmul_rn(v0, v0);
    for (int d = 1; d < D; ++d) {
        float v = emb[d * K + k];
        et[k * D + d] = v;
        ebT[k * D + d] = f2bf(v);
        s = __fadd_rn(s, __fmul_rn(v, v));  // sequential d (np axis-0 reduce)
    }
    e2[k] = s;
}

// ---- exact np-order dist for one (row, k), packed (distbits<<32)|k ----
__device__ __noinline__ unsigned long long exact_pack(
        const float* __restrict__ x, const float* __restrict__ et,
        const float* __restrict__ e2f, int row, int k) {
    const float* xr = x + (size_t)row * D;
    float r0 = __fmul_rn(xr[0], xr[0]), r1 = __fmul_rn(xr[1], xr[1]);
    float r2 = __fmul_rn(xr[2], xr[2]), r3 = __fmul_rn(xr[3], xr[3]);
    float r4 = __fmul_rn(xr[4], xr[4]), r5 = __fmul_rn(xr[5], xr[5]);
    float r6 = __fmul_rn(xr[6], xr[6]), r7 = __fmul_rn(xr[7], xr[7]);
    for (int i = 8; i < 64; i += 8) {
        r0 = __fadd_rn(r0, __fmul_rn(xr[i],     xr[i]));
        r1 = __fadd_rn(r1, __fmul_rn(xr[i + 1], xr[i + 1]));
        r2 = __fadd_rn(r2, __fmul_rn(xr[i + 2], xr[i + 2]));
        r3 = __fadd_rn(r3, __fmul_rn(xr[i + 3], xr[i + 3]));
        r4 = __fadd_rn(r4, __fmul_rn(xr[i + 4], xr[i + 4]));
        r5 = __fadd_rn(r5, __fmul_rn(xr[i + 5], xr[i + 5]));
        r6 = __fadd_rn(r6, __fmul_rn(xr[i + 6], xr[i + 6]));
        r7 = __fadd_rn(r7, __fmul_rn(xr[i + 7], xr[i + 7]));
    }
    float z2 = __fadd_rn(__fadd_rn(__fadd_rn(r0, r1), __fadd_rn(r2, r3)),
                         __fadd_rn(__fadd_rn(r4, r5), __fadd_rn(r6, r7)));
    const float* ep = et + (size_t)k * D;
    float a = 0.f;
    for (int d = 0; d < D; ++d) a = fmaf(xr[d], ep[d], a);  // sequential np chain
    float dist = __fsub_rn(__fadd_rn(z2, e2f[k]), __fmul_rn(2.0f, a));
    return ((unsigned long long)__float_as_uint(dist) << 32) | (unsigned)k;
}

// ---- K2: fused filter + recheck + gather. 4 waves x 32 rows = 128 rows ----
__global__ void __launch_bounds__(256)
vq_fused(const float* __restrict__ x, float* __restrict__ out,
         char* __restrict__ ws) {
    const float* et  = (const float*)(ws + WS_ET);
    const float* e2f = (const float*)(ws + WS_E2);
    const unsigned short* ebT = (const unsigned short*)(ws + WS_EBT);
    double* partials = (double*)(ws + WS_PARTIALS);

    __shared__ float le2[512];
    __shared__ unsigned long long lgmin[128];
    __shared__ unsigned cl[2048];
    __shared__ double red[256];
    __shared__ int ccnt;
    __shared__ int ovf;

    const int tid = threadIdx.x;
    const int wv = tid >> 6, lane = tid & 63;
    const int c15 = lane & 15;
    const int g = lane >> 4;
    const int kofs = g * 8;
    const int gr4 = g * 4;
    // XCD-bijective swizzle: 2048 blocks, 256/XCD contiguous (2048%8==0)
    const int bswz = ((int)blockIdx.x & 7) * 256 + ((int)blockIdx.x >> 3);
    const int blockRow0 = bswz * 128;
    const int rowBase = blockRow0 + wv * 32;   // this wave's 32 rows

    if (tid < 128) lgmin[tid] = 0xFFFFFFFFFFFFFFFFULL;
    if (tid == 0) { ccnt = 0; ovf = 0; }
    le2[tid] = e2f[tid];
    le2[tid + 256] = e2f[tid + 256];

    // hoist A: convert own x rows to bf16 fragments in registers (once)
    bf16x8 aA0, aA1, aB0, aB1;
#define LOADA(RT, A0, A1) { \
    const float* xp = x + ((size_t)(rowBase + (RT) * 16 + c15)) * D + kofs; \
    float4 p0 = *(const float4*)xp; \
    float4 p1 = *(const float4*)(xp + 4); \
    float4 p2 = *(const float4*)(xp + 32); \
    float4 p3 = *(const float4*)(xp + 36); \
    A0 = pack8(p0, p1); A1 = pack8(p2, p3); }
    LOADA(0, aA0, aA1) LOADA(1, aB0, aB1)
#undef LOADA

    __syncthreads();

    float m00 = INF32, m01 = INF32, m02 = INF32, m03 = INF32;
    float m10 = INF32, m11 = INF32, m12 = INF32, m13 = INF32;

    // lane's B-fragment column base; stride 1024 shorts per j
    const unsigned short* bbase = ebT + ((size_t)c15 << 6) + kofs;

    // sweep1: row minima of t = fmaf(-2, dot_bf, e2[k]); B double-buffered
#define SW1(A0, A1, M0, M1, M2, M3) { \
    f32x4 acc = {0.f, 0.f, 0.f, 0.f}; \
    acc = __builtin_amdgcn_mfma_f32_16x16x32_bf16(A0, bb0, acc, 0, 0, 0); \
    acc = __builtin_amdgcn_mfma_f32_16x16x32_bf16(A1, bb1, acc, 0, 0, 0); \
    M0 = fminf(M0, fmaf(-2.0f, acc[0], e2c)); \
    M1 = fminf(M1, fmaf(-2.0f, acc[1], e2c)); \
    M2 = fminf(M2, fmaf(-2.0f, acc[2], e2c)); \
    M3 = fminf(M3, fmaf(-2.0f, acc[3], e2c)); }

    {
        bf16x8 bb0 = *(const bf16x8*)bbase;
        bf16x8 bb1 = *(const bf16x8*)(bbase + 32);
        for (int j = 0; j < 32; ++j) {
            const unsigned short* np = bbase + (((j + 1) & 31) << 10);
            bf16x8 nb0 = *(const bf16x8*)np;          // prefetch j+1
            bf16x8 nb1 = *(const bf16x8*)(np + 32);
            float e2c = le2[j * 16 + c15];
            SW1(aA0, aA1, m00, m01, m02, m03)
            SW1(aB0, aB1, m10, m11, m12, m13)
            bb0 = nb0; bb1 = nb1;
        }
    }
#undef SW1

    // min across the 16 lanes (cols) of each lane-group, then add margin
#define RED(v) v = fminf(v, __shfl_xor(v, 1)); v = fminf(v, __shfl_xor(v, 2)); \
               v = fminf(v, __shfl_xor(v, 4)); v = fminf(v, __shfl_xor(v, 8)); \
               v += MARGIN;
    RED(m00) RED(m01) RED(m02) RED(m03)
    RED(m10) RED(m11) RED(m12) RED(m13)
#undef RED

    // sweep2: collect candidates t <= rowmin + MARGIN. NO CALLS in loop.
#define PUSH(RT, R) { int idx = atomicAdd(&ccnt, 1); \
    if (idx < 2048) cl[idx] = \
        ((unsigned)(wv * 32 + (RT) * 16 + gr4 + (R)) << 9) | (unsigned)kkl; \
    else ovf = 1; }

#define SW2(RT, A0, A1, M0, M1, M2, M3) { \
    f32x4 acc = {0.f, 0.f, 0.f, 0.f}; \
    acc = __builtin_amdgcn_mfma_f32_16x16x32_bf16(A0, bb0, acc, 0, 0, 0); \
    acc = __builtin_amdgcn_mfma_f32_16x16x32_bf16(A1, bb1, acc, 0, 0, 0); \
    if (fmaf(-2.0f, acc[0], e2c) <= M0) PUSH(RT, 0) \
    if (fmaf(-2.0f, acc[1], e2c) <= M1) PUSH(RT, 1) \
    if (fmaf(-2.0f, acc[2], e2c) <= M2) PUSH(RT, 2) \
    if (fmaf(-2.0f, acc[3], e2c) <= M3) PUSH(RT, 3) }

    {
        bf16x8 bb0 = *(const bf16x8*)bbase;
        bf16x8 bb1 = *(const bf16x8*)(bbase + 32);
        for (int j = 0; j < 32; ++j) {
            const unsigned short* np = bbase + (((j + 1) & 31) << 10);
            bf16x8 nb0 = *(const bf16x8*)np;          // prefetch j+1
            bf16x8 nb1 = *(const bf16x8*)(np + 32);
            const int kkl = j * 16 + c15;
            float e2c = le2[kkl];
            SW2(0, aA0, aA1, m00, m01, m02, m03)
            SW2(1, aB0, aB1, m10, m11, m12, m13)
            bb0 = nb0; bb1 = nb1;
        }
    }
#undef SW2
#undef PUSH

    __syncthreads();
    // exact recheck of listed candidates (block-private rows -> LDS atomicMin)
    const int cnt = (ccnt < 2048) ? ccnt : 2048;
    for (int i = tid; i < cnt; i += 256) {
        unsigned e = cl[i];
        int rowLocal = (int)(e >> 9);
        int k = (int)(e & 0x1ffu);
        atomicMin(&lgmin[rowLocal], exact_pack(x, et, e2f, blockRow0 + rowLocal, k));
    }
    // overflow fallback: full exact rescan (never taken: ~220 cands << 2048)
    if (ovf) {
        for (int p = tid; p < 128 * 512; p += 256)
            atomicMin(&lgmin[p >> 9],
                      exact_pack(x, et, e2f, blockRow0 + (p >> 9), p & 0x1ff));
    }
    __syncthreads();

    // gather winning code; out = fl(x + fl(q - x)); fp64 loss partial.
    // 2 lanes per row: tid = 2*rowLocal + half, each lane does 8 float4s.
    const int rowL = tid >> 1;
    const int half = tid & 1;
    const int row = blockRow0 + rowL;
    const int kb = (int)(lgmin[rowL] & 0xFFFFFFFFULL);
    const float4* cq = (const float4*)(et + (size_t)kb * D) + half * 8;
    const float4* xr = (const float4*)(x + (size_t)row * D) + half * 8;
    float4* outr = (float4*)(out + (size_t)row * D) + half * 8;
    double rs = 0.0;
#define OUTQ(G) { \
        float4 e4 = cq[G]; float4 xv = xr[G]; float4 o; \
        float d0 = __fsub_rn(e4.x, xv.x); \
        float d1 = __fsub_rn(e4.y, xv.y); \
        float d2 = __fsub_rn(e4.z, xv.z); \
        float d3 = __fsub_rn(e4.w, xv.w); \
        o.x = __fadd_rn(xv.x, d0); \
        o.y = __fadd_rn(xv.y, d1); \
        o.z = __fadd_rn(xv.z, d2); \
        o.w = __fadd_rn(xv.w, d3); \
        outr[G] = o; \
        rs += (double)__fmul_rn(d0, d0) + (double)__fmul_rn(d1, d1) + \
              (double)__fmul_rn(d2, d2) + (double)__fmul_rn(d3, d3); }
    OUTQ(0) OUTQ(1) OUTQ(2) OUTQ(3) OUTQ(4) OUTQ(5) OUTQ(6) OUTQ(7)
#undef OUTQ

    red[tid] = rs;
    __syncthreads();
    for (int s = 128; s > 0; s >>= 1) {
        if (tid < s) red[tid] += red[tid + s];
        __syncthreads();
    }
    if (tid == 0) partials[bswz] = red[0];
}

// ---- K3: finalize loss over 2048 partials ----
__global__ void __launch_bounds__(256) vq_finalize(float* __restrict__ out, char* ws) {
    const double* partials = (const double*)(ws + WS_PARTIALS);
    __shared__ double red[256];
    double s = 0.0;
#pragma unroll
    for (int i = 0; i < 8; ++i) s += partials[threadIdx.x + 256 * i];
    red[threadIdx.x] = s;
    __syncthreads();
    for (int st = 128; st > 0; st >>= 1) {
        if (threadIdx.x < st) red[threadIdx.x] += red[threadIdx.x + st];
        __syncthreads();
    }
    if (threadIdx.x == 0) {
        out[16777216] = (float)(1.25 * red[0] / 16777216.0);
    }
}

extern "C" void kernel_launch(void* const* d_in, const int* in_sizes, int n_in,
                              void* d_out, int out_size, void* d_ws, size_t ws_size,
                              hipStream_t stream) {
    const float* x   = (const float*)d_in[0];
    const float* emb = (const float*)d_in[1];
    float* out = (float*)d_out;
    char* ws = (char*)d_ws;

    vq_prep<<<8, 64, 0, stream>>>(emb, ws);
    vq_fused<<<NROWS / 128, 256, 0, stream>>>(x, out, ws);
    vq_finalize<<<1, 256, 0, stream>>>(out, ws);
}

// Round 14
// 184.090 us; speedup vs baseline: 1.2845x; 1.2845x over previous
//
#include <hip/hip_runtime.h>

// VectorQuantizer: fused MFMA bf16 filter + bit-exact numpy recheck + gather.
// x [64,64,64,64] f32 -> flat [N=262144, D=64]; emb [D=64, K=512].
// out = concat(quantized_st flat [16777216], loss [1]) as f32.
//
// R14: kill the per-j L2 round trip for B — stage the WHOLE 64KB bf16
// codebook in LDS once per block (8-wave/512-thread blocks, 256 rows),
// XOR-swizzled at 16B granules (slot = s ^ (row&7)) so the wave's
// ds_read_b128 spreads across all 8 bank-groups (BW-floor, no conflict
// waste). Sweeps read B from LDS: no global dependency in the j-loop.
// Per-wave state stays the R12/R13-proven spill-free 32 rows/wave.
// LDS ~76KB -> 2 blocks/CU -> 16 waves/CU ceiling; grid 1024.
//
// Exact numpy semantics (proven absmax 0.0 R2/R5-R13) on candidates:
//   dist = fl(fl(z2+e2[k]) - 2*dot), dot = sequential fmaf d=0..63,
//   z2 = np pairwise_sum, e2 = sequential d-ascending, argmin strict-<
//   first-occurrence == lexicographic u64 min of (distbits<<32)|k [dist>0].
// bf16 filter: t = fmaf(-2, acc, e2c) in BOTH sweeps; MARGIN=0.09 >>
// 2*max bf16-vs-np t-error (~0.04) (R6-R13 validated).
//
// ws layout (bytes):
//   0      : float  et[512*64]    131072  (f32 codebook, code-major)
//   131072 : float  e2[512]         2048  (np-order norms, exact)
//   133120 : u16    ebT[512*64]    65536  (bf16 codebook, code-major)
//   198656 : double partials[1024]  8192  (per-block loss partials)

#define NROWS 262144
#define D 64
#define K 512
#define MARGIN 0.09f
#define INF32 3.4e38f

#define WS_ET 0
#define WS_E2 131072
#define WS_EBT 133120
#define WS_PARTIALS 198656

typedef __attribute__((ext_vector_type(8))) short bf16x8;
typedef __attribute__((ext_vector_type(4))) float f32x4;

union ClRed { unsigned cl[2048]; double red[512]; };

__device__ inline unsigned short f2bf(float f) {  // RTNE, finite inputs
    unsigned u = __float_as_uint(f);
    u += 0x7fffu + ((u >> 16) & 1u);
    return (unsigned short)(u >> 16);
}
__device__ inline unsigned pack_bf2(float lo, float hi) {
    unsigned ulo = __float_as_uint(lo); ulo += 0x7fffu + ((ulo >> 16) & 1u);
    unsigned uhi = __float_as_uint(hi); uhi += 0x7fffu + ((uhi >> 16) & 1u);
    return (ulo >> 16) | (uhi & 0xffff0000u);
}
__device__ inline bf16x8 pack8(float4 p, float4 q) {
    union { unsigned u[4]; bf16x8 v; } r;
    r.u[0] = pack_bf2(p.x, p.y); r.u[1] = pack_bf2(p.z, p.w);
    r.u[2] = pack_bf2(q.x, q.y); r.u[3] = pack_bf2(q.z, q.w);
    return r.v;
}

// ---- K1: codebook prep (8 blocks x 64 threads, one code per thread) ----
__global__ void __launch_bounds__(64) vq_prep(const float* __restrict__ emb, char* ws) {
    float* e2 = (float*)(ws + WS_E2);
    float* et = (float*)(ws + WS_ET);
    unsigned short* ebT = (unsigned short*)(ws + WS_EBT);
    int k = blockIdx.x * 64 + threadIdx.x;
    float v0 = emb[k];
    et[k * D] = v0;
    ebT[k * D] = f2bf(v0);
    float s = __fmul_rn(v0, v0);
    for (int d = 1; d < D; ++d) {
        float v = emb[d * K + k];
        et[k * D + d] = v;
        ebT[k * D + d] = f2bf(v);
        s = __fadd_rn(s, __fmul_rn(v, v));  // sequential d (np axis-0 reduce)
    }
    e2[k] = s;
}

// ---- exact np-order dist for one (row, k), packed (distbits<<32)|k ----
__device__ __noinline__ unsigned long long exact_pack(
        const float* __restrict__ x, const float* __restrict__ et,
        const float* __restrict__ e2f, int row, int k) {
    const float* xr = x + (size_t)row * D;
    float r0 = __fmul_rn(xr[0], xr[0]), r1 = __fmul_rn(xr[1], xr[1]);
    float r2 = __fmul_rn(xr[2], xr[2]), r3 = __fmul_rn(xr[3], xr[3]);
    float r4 = __fmul_rn(xr[4], xr[4]), r5 = __fmul_rn(xr[5], xr[5]);
    float r6 = __fmul_rn(xr[6], xr[6]), r7 = __fmul_rn(xr[7], xr[7]);
    for (int i = 8; i < 64; i += 8) {
        r0 = __fadd_rn(r0, __fmul_rn(xr[i],     xr[i]));
        r1 = __fadd_rn(r1, __fmul_rn(xr[i + 1], xr[i + 1]));
        r2 = __fadd_rn(r2, __fmul_rn(xr[i + 2], xr[i + 2]));
        r3 = __fadd_rn(r3, __fmul_rn(xr[i + 3], xr[i + 3]));
        r4 = __fadd_rn(r4, __fmul_rn(xr[i + 4], xr[i + 4]));
        r5 = __fadd_rn(r5, __fmul_rn(xr[i + 5], xr[i + 5]));
        r6 = __fadd_rn(r6, __fmul_rn(xr[i + 6], xr[i + 6]));
        r7 = __fadd_rn(r7, __fmul_rn(xr[i + 7], xr[i + 7]));
    }
    float z2 = __fadd_rn(__fadd_rn(__fadd_rn(r0, r1), __fadd_rn(r2, r3)),
                         __fadd_rn(__fadd_rn(r4, r5), __fadd_rn(r6, r7)));
    const float* ep = et + (size_t)k * D;
    float a = 0.f;
    for (int d = 0; d < D; ++d) a = fmaf(xr[d], ep[d], a);  // sequential np chain
    float dist = __fsub_rn(__fadd_rn(z2, e2f[k]), __fmul_rn(2.0f, a));
    return ((unsigned long long)__float_as_uint(dist) << 32) | (unsigned)k;
}

// ---- K2: fused filter + recheck + gather. 8 waves x 32 rows = 256 rows ----
__global__ void __launch_bounds__(512)
vq_fused(const float* __restrict__ x, float* __restrict__ out,
         char* __restrict__ ws) {
    const float* et  = (const float*)(ws + WS_ET);
    const float* e2f = (const float*)(ws + WS_E2);
    const unsigned short* ebT = (const unsigned short*)(ws + WS_EBT);
    double* partials = (double*)(ws + WS_PARTIALS);

    __shared__ unsigned short ebs[32768];      // 64KB: FULL codebook, swizzled
    __shared__ float le2[512];
    __shared__ unsigned long long lgmin[256];
    __shared__ ClRed u;                        // cl[2048] / red[512]
    __shared__ int ccnt;
    __shared__ int ovf;

    const int tid = threadIdx.x;
    const int wv = tid >> 6, lane = tid & 63;
    const int c15 = lane & 15;
    const int g = lane >> 4;
    const int kofs = g * 8;
    const int gr4 = g * 4;
    // XCD-bijective swizzle: 1024 blocks, 128/XCD contiguous (1024%8==0)
    const int bswz = ((int)blockIdx.x & 7) * 128 + ((int)blockIdx.x >> 3);
    const int blockRow0 = bswz * 256;
    const int rowBase = blockRow0 + wv * 32;   // this wave's 32 rows

    if (tid < 256) lgmin[tid] = 0xFFFFFFFFFFFFFFFFULL;
    if (tid == 0) { ccnt = 0; ovf = 0; }
    if (tid < 512) le2[tid] = e2f[tid];

    // stage full bf16 codebook into LDS, swizzled: granule s -> s ^ (row&7)
    {
        const uint4* src = (const uint4*)ebT;    // 4096 16B granules
        uint4* dstv = (uint4*)ebs;
        for (int i = tid; i < 4096; i += 512) {
            int row = i >> 3, s = i & 7;
            dstv[(row << 3) + (s ^ (row & 7))] = src[i];
        }
    }

    // hoist A: convert own x rows to bf16 fragments in registers (once)
    bf16x8 aA0, aA1, aB0, aB1;
#define LOADA(RT, A0, A1) { \
    const float* xp = x + ((size_t)(rowBase + (RT) * 16 + c15)) * D + kofs; \
    float4 p0 = *(const float4*)xp; \
    float4 p1 = *(const float4*)(xp + 4); \
    float4 p2 = *(const float4*)(xp + 32); \
    float4 p3 = *(const float4*)(xp + 36); \
    A0 = pack8(p0, p1); A1 = pack8(p2, p3); }
    LOADA(0, aA0, aA1) LOADA(1, aB0, aB1)
#undef LOADA

    __syncthreads();   // codebook staged

    float m00 = INF32, m01 = INF32, m02 = INF32, m03 = INF32;
    float m10 = INF32, m11 = INF32, m12 = INF32, m13 = INF32;

    // sweep1: row minima of t = fmaf(-2, dot_bf, e2[k]); B from LDS
#define SW1(A0, A1, M0, M1, M2, M3) { \
    f32x4 acc = {0.f, 0.f, 0.f, 0.f}; \
    acc = __builtin_amdgcn_mfma_f32_16x16x32_bf16(A0, bb0, acc, 0, 0, 0); \
    acc = __builtin_amdgcn_mfma_f32_16x16x32_bf16(A1, bb1, acc, 0, 0, 0); \
    M0 = fminf(M0, fmaf(-2.0f, acc[0], e2c)); \
    M1 = fminf(M1, fmaf(-2.0f, acc[1], e2c)); \
    M2 = fminf(M2, fmaf(-2.0f, acc[2], e2c)); \
    M3 = fminf(M3, fmaf(-2.0f, acc[3], e2c)); }

    for (int j = 0; j < 32; ++j) {
        const int kkl = j * 16 + c15;
        const int rsw = kkl & 7;
        const unsigned short* bp = ebs + (kkl << 6);
        bf16x8 bb0 = *(const bf16x8*)(bp + ((g ^ rsw) << 3));
        bf16x8 bb1 = *(const bf16x8*)(bp + (((g + 4) ^ rsw) << 3));
        float e2c = le2[kkl];
        SW1(aA0, aA1, m00, m01, m02, m03)
        SW1(aB0, aB1, m10, m11, m12, m13)
    }
#undef SW1

    // min across the 16 lanes (cols) of each lane-group, then add margin
#define RED(v) v = fminf(v, __shfl_xor(v, 1)); v = fminf(v, __shfl_xor(v, 2)); \
               v = fminf(v, __shfl_xor(v, 4)); v = fminf(v, __shfl_xor(v, 8)); \
               v += MARGIN;
    RED(m00) RED(m01) RED(m02) RED(m03)
    RED(m10) RED(m11) RED(m12) RED(m13)
#undef RED

    // sweep2: collect candidates t <= rowmin + MARGIN. NO CALLS in loop.
#define PUSH(RT, R) { int idx = atomicAdd(&ccnt, 1); \
    if (idx < 2048) u.cl[idx] = \
        ((unsigned)(wv * 32 + (RT) * 16 + gr4 + (R)) << 9) | (unsigned)kkl; \
    else ovf = 1; }

#define SW2(RT, A0, A1, M0, M1, M2, M3) { \
    f32x4 acc = {0.f, 0.f, 0.f, 0.f}; \
    acc = __builtin_amdgcn_mfma_f32_16x16x32_bf16(A0, bb0, acc, 0, 0, 0); \
    acc = __builtin_amdgcn_mfma_f32_16x16x32_bf16(A1, bb1, acc, 0, 0, 0); \
    if (fmaf(-2.0f, acc[0], e2c) <= M0) PUSH(RT, 0) \
    if (fmaf(-2.0f, acc[1], e2c) <= M1) PUSH(RT, 1) \
    if (fmaf(-2.0f, acc[2], e2c) <= M2) PUSH(RT, 2) \
    if (fmaf(-2.0f, acc[3], e2c) <= M3) PUSH(RT, 3) }

    for (int j = 0; j < 32; ++j) {
        const int kkl = j * 16 + c15;
        const int rsw = kkl & 7;
        const unsigned short* bp = ebs + (kkl << 6);
        bf16x8 bb0 = *(const bf16x8*)(bp + ((g ^ rsw) << 3));
        bf16x8 bb1 = *(const bf16x8*)(bp + (((g + 4) ^ rsw) << 3));
        float e2c = le2[kkl];
        SW2(0, aA0, aA1, m00, m01, m02, m03)
        SW2(1, aB0, aB1, m10, m11, m12, m13)
    }
#undef SW2
#undef PUSH

    __syncthreads();
    // exact recheck of listed candidates (block-private rows -> LDS atomicMin)
    const int cnt = (ccnt < 2048) ? ccnt : 2048;
    for (int i = tid; i < cnt; i += 512) {
        unsigned e = u.cl[i];
        int rowLocal = (int)(e >> 9);
        int k = (int)(e & 0x1ffu);
        atomicMin(&lgmin[rowLocal], exact_pack(x, et, e2f, blockRow0 + rowLocal, k));
    }
    // overflow fallback: full exact rescan (never taken: ~440 cands << 2048)
    if (ovf) {
        for (int p = tid; p < 256 * 512; p += 512)
            atomicMin(&lgmin[p >> 9],
                      exact_pack(x, et, e2f, blockRow0 + (p >> 9), p & 0x1ff));
    }
    __syncthreads();

    // gather winning code; out = fl(x + fl(q - x)); fp64 loss partial.
    // 2 lanes per row: tid = 2*rowLocal + half, each lane does 8 float4s.
    const int rowL = tid >> 1;
    const int half = tid & 1;
    const int row = blockRow0 + rowL;
    const int kb = (int)(lgmin[rowL] & 0xFFFFFFFFULL);
    const float4* cq = (const float4*)(et + (size_t)kb * D) + half * 8;
    const float4* xr = (const float4*)(x + (size_t)row * D) + half * 8;
    float4* outr = (float4*)(out + (size_t)row * D) + half * 8;
    double rs = 0.0;
#define OUTQ(G) { \
        float4 e4 = cq[G]; float4 xv = xr[G]; float4 o; \
        float d0 = __fsub_rn(e4.x, xv.x); \
        float d1 = __fsub_rn(e4.y, xv.y); \
        float d2 = __fsub_rn(e4.z, xv.z); \
        float d3 = __fsub_rn(e4.w, xv.w); \
        o.x = __fadd_rn(xv.x, d0); \
        o.y = __fadd_rn(xv.y, d1); \
        o.z = __fadd_rn(xv.z, d2); \
        o.w = __fadd_rn(xv.w, d3); \
        outr[G] = o; \
        rs += (double)__fmul_rn(d0, d0) + (double)__fmul_rn(d1, d1) + \
              (double)__fmul_rn(d2, d2) + (double)__fmul_rn(d3, d3); }
    OUTQ(0) OUTQ(1) OUTQ(2) OUTQ(3) OUTQ(4) OUTQ(5) OUTQ(6) OUTQ(7)
#undef OUTQ

    u.red[tid] = rs;   // safe: all cl reads completed before the last barrier
    __syncthreads();
    for (int s = 256; s > 0; s >>= 1) {
        if (tid < s) u.red[tid] += u.red[tid + s];
        __syncthreads();
    }
    if (tid == 0) partials[bswz] = u.red[0];
}

// ---- K3: finalize loss over 1024 partials ----
__global__ void __launch_bounds__(256) vq_finalize(float* __restrict__ out, char* ws) {
    const double* partials = (const double*)(ws + WS_PARTIALS);
    __shared__ double red[256];
    double s = partials[threadIdx.x] + partials[threadIdx.x + 256] +
               partials[threadIdx.x + 512] + partials[threadIdx.x + 768];
    red[threadIdx.x] = s;
    __syncthreads();
    for (int st = 128; st > 0; st >>= 1) {
        if (threadIdx.x < st) red[threadIdx.x] += red[threadIdx.x + st];
        __syncthreads();
    }
    if (threadIdx.x == 0) {
        out[16777216] = (float)(1.25 * red[0] / 16777216.0);
    }
}

extern "C" void kernel_launch(void* const* d_in, const int* in_sizes, int n_in,
                              void* d_out, int out_size, void* d_ws, size_t ws_size,
                              hipStream_t stream) {
    const float* x   = (const float*)d_in[0];
    const float* emb = (const float*)d_in[1];
    float* out = (float*)d_out;
    char* ws = (char*)d_ws;

    vq_prep<<<8, 64, 0, stream>>>(emb, ws);
    vq_fused<<<NROWS / 256, 512, 0, stream>>>(x, out, ws);
    vq_finalize<<<1, 256, 0, stream>>>(out, ws);
}